// Round 12
// baseline (142.217 us; speedup 1.0000x reference)
//
#include <hip/hip_runtime.h>
#include <math.h>

// HardMoE classifier: B=131072, D=1024, E=6, L=2, fp32.
// r10/r11 identical at 118us regardless of occupancy (16 vs 24 waves/CU)
// => not occupancy-bound. Little's law: 4KB in flight per wave * ~10% duty
// = 4.4 TB/s (measured 4.35). THIS round: R=4 rows/iteration -> 16KB load
// burst per wave per iter (4x in-flight bytes), gate weights bf16 in LDS
// (12KB, reads amortized over 4 rows), expert bf16 LDS (24KB, validated
// r10: absmax .0156 << .061). Tie fallback re-dots fp32 gate_w from GLOBAL
// (L2-hot, rare ~5%) with Kahan; threshold 0.02 covers bf16 logit err ~5e-3.
// LESSON (r2/r8): never pass launch_bounds min-waves arg. DPP reductions.

static constexpr int En = 6;
static constexpr int NQ = 32768;   // 131072 rows / 4
static constexpr int NW = 4096;    // 512 blocks * 8 waves

template <int CTRL>
__device__ __forceinline__ float dpp_row_add(float v) {
  return v + __int_as_float(__builtin_amdgcn_update_dpp(
                 0, __float_as_int(v), CTRL, 0xf, 0xf, true));
}

// Full 64-lane sum, broadcast via readlane(63) -> sgpr.
__device__ __forceinline__ float wave_sum_bcast(float v) {
  v = dpp_row_add<0x111>(v);  // row_shr:1
  v = dpp_row_add<0x112>(v);  // row_shr:2
  v = dpp_row_add<0x114>(v);  // row_shr:4
  v = dpp_row_add<0x118>(v);  // row_shr:8
  v = dpp_row_add<0x142>(v);  // row_bcast:15
  v = dpp_row_add<0x143>(v);  // row_bcast:31
  return __int_as_float(__builtin_amdgcn_readlane(__float_as_int(v), 63));
}

__device__ __forceinline__ float dot4(float4 a, float4 b) {
  return fmaf(a.x, b.x, fmaf(a.y, b.y, fmaf(a.z, b.z, a.w * b.w)));
}

__device__ __forceinline__ ushort f2bf(float f) {  // RNE float->bf16
  unsigned u = __float_as_uint(f);
  u += 0x7FFFu + ((u >> 16) & 1u);
  return (ushort)(u >> 16);
}

__device__ __forceinline__ float4 bf2f4(ushort4 u) {
  return make_float4(__uint_as_float(((unsigned)u.x) << 16),
                     __uint_as_float(((unsigned)u.y) << 16),
                     __uint_as_float(((unsigned)u.z) << 16),
                     __uint_as_float(((unsigned)u.w) << 16));
}

__global__ __launch_bounds__(512) void hardmoe_kernel(
    const float* __restrict__ cls, const float* __restrict__ gate_w,
    const float* __restrict__ gate_b, const float* __restrict__ expert_w,
    const float* __restrict__ expert_b, float* __restrict__ out) {
  // Layout-preserving bf16: ushort4 index i == float4 index i of the fp32
  // original, so the read pattern [e*256 + t*64 + lane] matches c[t].
  __shared__ ushort4 ldsG16[1536];  // gate_w  bf16: 6x1024  = 12 KB
  __shared__ ushort4 ldsE16[3072];  // expert_w bf16: 6x2x1024 = 24 KB
  __shared__ float ldsGb[6];
  __shared__ float ldsEb[12];

  const int tid = threadIdx.x;
  const int lane = tid & 63;

  {
    const float4* __restrict__ gw4 = (const float4*)gate_w;
    const float4* __restrict__ ew4 = (const float4*)expert_w;
#pragma unroll
    for (int k = 0; k < 3; ++k) {
      const int i = tid + k * 512;
      const float4 v = gw4[i];
      ldsG16[i] = make_ushort4(f2bf(v.x), f2bf(v.y), f2bf(v.z), f2bf(v.w));
    }
#pragma unroll
    for (int k = 0; k < 6; ++k) {
      const int i = tid + k * 512;
      const float4 v = ew4[i];
      ldsE16[i] = make_ushort4(f2bf(v.x), f2bf(v.y), f2bf(v.z), f2bf(v.w));
    }
    if (tid < 6) ldsGb[tid] = gate_b[tid];
    else if (tid < 18) ldsEb[tid - 6] = expert_b[tid - 6];
  }
  __syncthreads();

  const float4* __restrict__ cls4 = (const float4*)cls;
  const float4* __restrict__ gw4 = (const float4*)gate_w;
  const int gwid = blockIdx.x * 8 + (tid >> 6);

  for (int q = gwid; q < NQ; q += NW) {
    const int row = q * 4;
    // 16 dwordx4 issued in one burst: 16KB in flight per wave.
    float4 c[4][4];
#pragma unroll
    for (int r = 0; r < 4; ++r)
#pragma unroll
      for (int t = 0; t < 4; ++t)
        c[r][t] = cls4[(size_t)(row + r) * 256 + t * 64 + lane];

    // ---- gate logits (bf16 weights) + fused per-row argmax ----
    int best[4] = {0, 0, 0, 0};
    float bv[4], sec[4];
#pragma unroll
    for (int r = 0; r < 4; ++r) { bv[r] = -INFINITY; sec[r] = -INFINITY; }

#pragma unroll
    for (int e = 0; e < En; ++e) {
      float s[4] = {0.f, 0.f, 0.f, 0.f};
#pragma unroll
      for (int t = 0; t < 4; ++t) {
        const float4 W = bf2f4(ldsG16[e * 256 + t * 64 + lane]);
#pragma unroll
        for (int r = 0; r < 4; ++r) s[r] += dot4(c[r][t], W);
      }
      const float gb = ldsGb[e];
#pragma unroll
      for (int r = 0; r < 4; ++r) {
        const float v = wave_sum_bcast(s[r]) + gb;
        if (v > bv[r]) {
          sec[r] = bv[r]; bv[r] = v; best[r] = e;
        } else if (v > sec[r]) {
          sec[r] = v;
        }
      }
    }

    // Near-tie fallback (~5%): fp32 Kahan re-dot, gate_w from global
    // (24KB, L2-hot). Threshold 0.02 >> bf16 logit err ~5e-3.
#pragma unroll
    for (int r = 0; r < 4; ++r) {
      if (__builtin_expect(bv[r] - sec[r] < 0.02f, 0)) {
        float kb = -INFINITY;
        int ki = 0;
#pragma unroll
        for (int e = 0; e < En; ++e) {
          float sum = 0.f, comp = 0.f;
#pragma unroll
          for (int t = 0; t < 4; ++t) {
            const float4 w = gw4[e * 256 + t * 64 + lane];
            const float4 cc = c[r][t];
            const float pr[4] = {cc.x * w.x, cc.y * w.y, cc.z * w.z,
                                 cc.w * w.w};
#pragma unroll
            for (int j = 0; j < 4; ++j) {
              const float y = pr[j] - comp;
              const float tt = sum + y;
              comp = (tt - sum) - y;
              sum = tt;
            }
          }
          const float v = wave_sum_bcast(sum) + wave_sum_bcast(comp) + ldsGb[e];
          if (v > kb) { kb = v; ki = e; }
        }
        best[r] = ki;
      }
    }

    // ---- chosen experts from bf16 LDS ----
    float o0[4], o1[4];
#pragma unroll
    for (int r = 0; r < 4; ++r) {
      const ushort4* e4 = ldsE16 + best[r] * 512;
      float a0 = 0.f, a1 = 0.f;
#pragma unroll
      for (int t = 0; t < 4; ++t) {
        a0 += dot4(c[r][t], bf2f4(e4[t * 64 + lane]));
        a1 += dot4(c[r][t], bf2f4(e4[256 + t * 64 + lane]));
      }
      o0[r] = wave_sum_bcast(a0) + ldsEb[best[r] * 2 + 0];
      o1[r] = wave_sum_bcast(a1) + ldsEb[best[r] * 2 + 1];
    }

    if (lane == 0) {
      ((float4*)out)[q * 2 + 0] = make_float4(o0[0], o1[0], o0[1], o1[1]);
      ((float4*)out)[q * 2 + 1] = make_float4(o0[2], o1[2], o0[3], o1[3]);
    }
  }
}

extern "C" void kernel_launch(void* const* d_in, const int* in_sizes, int n_in,
                              void* d_out, int out_size, void* d_ws,
                              size_t ws_size, hipStream_t stream) {
  const float* cls = (const float*)d_in[0];
  const float* gate_w = (const float*)d_in[1];
  const float* gate_b = (const float*)d_in[2];
  const float* expert_w = (const float*)d_in[3];
  const float* expert_b = (const float*)d_in[4];
  float* out = (float*)d_out;

  // 512 blocks * 512 threads; each wave: 8 quads of 4 rows.
  hipLaunchKernelGGL(hardmoe_kernel, dim3(512), dim3(512), 0, stream, cls,
                     gate_w, gate_b, expert_w, expert_b, out);
}